// Round 2
// baseline (521.766 us; speedup 1.0000x reference)
//
#include <hip/hip_runtime.h>
#include <hip/hip_bf16.h>
#include <stdint.h>

#define B_ 2
#define S_ 2048
#define D_ 1024
#define H_ 16
#define DH 64

typedef __attribute__((ext_vector_type(4))) float f32x4;
typedef __attribute__((ext_vector_type(8))) short s16x8;
typedef __attribute__((ext_vector_type(4))) short s16x4;

__device__ inline short f2bf(float f) {
  union { float f; unsigned u; } v; v.f = f;
  unsigned r = (v.u + 0x7fffu + ((v.u >> 16) & 1u)) >> 16;
  return (short)r;
}

__global__ __launch_bounds__(256) void cvt_f32_bf16(const float* __restrict__ in,
                                                    short* __restrict__ out, int n) {
  int i = (blockIdx.x * 256 + threadIdx.x) * 4;
  if (i < n) {
    float4 v = *(const float4*)(in + i);
    s16x4 o;
    o.x = f2bf(v.x); o.y = f2bf(v.y); o.z = f2bf(v.z); o.w = f2bf(v.w);
    *(s16x4*)(out + i) = o;
  }
}

// out[n][k] = (bf16) in[k][n], square D_ x D_
__global__ __launch_bounds__(256) void transpose_cvt(const float* __restrict__ in,
                                                     short* __restrict__ out) {
  __shared__ float tile[32][33];
  int bx = blockIdx.x, by = blockIdx.y;
  int x = bx * 32 + threadIdx.x;
#pragma unroll
  for (int i = 0; i < 32; i += 8) {
    int y = by * 32 + threadIdx.y + i;
    tile[threadIdx.y + i][threadIdx.x] = in[(size_t)y * D_ + x];
  }
  __syncthreads();
  int ox = by * 32 + threadIdx.x;
#pragma unroll
  for (int i = 0; i < 32; i += 8) {
    int oy = bx * 32 + threadIdx.y + i;
    out[(size_t)oy * D_ + ox] = f2bf(tile[threadIdx.x][threadIdx.y + i]);
  }
}

__device__ inline void gload_lds16(const void* g, void* l) {
  __builtin_amdgcn_global_load_lds(
      (const __attribute__((address_space(1))) unsigned*)g,
      (__attribute__((address_space(3))) unsigned*)l, 16, 0, 0);
}

#define BM 128
#define BN 128
#define BK 32

// C[M][N] = A[M][K] * Bt[N][K]^T + bias ; A,Bt bf16 ; C bf16 or f32
__global__ __launch_bounds__(256) void gemm_bt(const short* __restrict__ A,
                                               const short* __restrict__ Bt,
                                               const float* __restrict__ bias,
                                               void* __restrict__ C,
                                               int M, int N, int K, int f32out) {
  __shared__ __align__(16) short As[BM * BK];
  __shared__ __align__(16) short Bs[BN * BK];
  int tid = threadIdx.x;
  int lane = tid & 63, wave = tid >> 6;
  int l15 = lane & 15, l4 = lane >> 4;
  int ntn = N / BN;
  int bm = blockIdx.x / ntn, bn = blockIdx.x % ntn;
  int row0 = bm * BM, col0 = bn * BN;
  int wm = (wave >> 1) * 64, wn = (wave & 1) * 64;

  f32x4 acc[4][4] = {};

  for (int k0 = 0; k0 < K; k0 += BK) {
    __syncthreads();
#pragma unroll
    for (int it = 0; it < 2; ++it) {
      int ch = it * 256 + tid;
      int r = ch >> 2, c = (ch & 3) * 8;
      int ldsbase = (it * 256 + wave * 64) * 8;  // elems; HW adds lane*16B
      gload_lds16(A + (size_t)(row0 + r) * K + k0 + c, &As[ldsbase]);
      gload_lds16(Bt + (size_t)(col0 + r) * K + k0 + c, &Bs[ldsbase]);
    }
    __syncthreads();
    s16x8 af[4], bf[4];
#pragma unroll
    for (int mf = 0; mf < 4; ++mf)
      af[mf] = *(const s16x8*)&As[(wm + mf * 16 + l15) * BK + l4 * 8];
#pragma unroll
    for (int nf = 0; nf < 4; ++nf)
      bf[nf] = *(const s16x8*)&Bs[(wn + nf * 16 + l15) * BK + l4 * 8];
#pragma unroll
    for (int mf = 0; mf < 4; ++mf)
#pragma unroll
      for (int nf = 0; nf < 4; ++nf)
        acc[mf][nf] = __builtin_amdgcn_mfma_f32_16x16x32_bf16(af[mf], bf[nf],
                                                              acc[mf][nf], 0, 0, 0);
  }

#pragma unroll
  for (int nf = 0; nf < 4; ++nf) {
    int gcol = col0 + wn + nf * 16 + l15;
    float bv = bias[gcol];
#pragma unroll
    for (int mf = 0; mf < 4; ++mf) {
#pragma unroll
      for (int r = 0; r < 4; ++r) {
        int grow = row0 + wm + mf * 16 + l4 * 4 + r;
        float v = acc[mf][nf][r] + bv;
        if (f32out)
          ((float*)C)[(size_t)grow * N + gcol] = v;
        else
          ((short*)C)[(size_t)grow * N + gcol] = f2bf(v);
      }
    }
  }
}

#define QB 128
#define NB 64

// q,k,v: bf16 (B,S,H*DH). mask int32, gp f32: (B,S,S). ctx out bf16 (B,S,H*DH)
__global__ __launch_bounds__(256) void attn_fused(const short* __restrict__ Qp,
                                                  const short* __restrict__ Kp,
                                                  const short* __restrict__ Vp,
                                                  const int* __restrict__ mask,
                                                  const float* __restrict__ gp,
                                                  short* __restrict__ ctx) {
  __shared__ __align__(16) short Vt[DH][72];     // [d][kv], padded
  __shared__ __align__(16) short Pl[4][32][72];  // per-wave P*gp, padded
  int tid = threadIdx.x, lane = tid & 63, wave = tid >> 6;
  int l15 = lane & 15, l4 = lane >> 4;
  int qtile = blockIdx.x;  // 0..15
  int bh = blockIdx.y;     // 0..31
  int b = bh >> 4, h = bh & 15;
  int q0 = qtile * QB;
  int wq = wave * 32;

  const short* Qbase = Qp + (size_t)b * S_ * D_ + (size_t)h * DH;
  const short* Kbase = Kp + (size_t)b * S_ * D_ + (size_t)h * DH;
  const short* Vbase = Vp + (size_t)b * S_ * D_ + (size_t)h * DH;

  s16x8 qf[2][2];
#pragma unroll
  for (int mf = 0; mf < 2; ++mf)
#pragma unroll
    for (int ks = 0; ks < 2; ++ks)
      qf[mf][ks] = *(const s16x8*)(Qbase + (size_t)(q0 + wq + mf * 16 + l15) * D_ +
                                   ks * 32 + l4 * 8);

  float mrun[2][4], lrun[2][4];
  f32x4 oacc[2][4] = {};
#pragma unroll
  for (int mf = 0; mf < 2; ++mf)
#pragma unroll
    for (int r = 0; r < 4; ++r) { mrun[mf][r] = -INFINITY; lrun[mf][r] = 0.f; }

  for (int kv0 = 0; kv0 < S_; kv0 += NB) {
    __syncthreads();  // protect Vt before overwrite
    {
      int kvr = tid >> 2;
      int dc = (tid & 3) * 16;
      const short* src = Vbase + (size_t)(kv0 + kvr) * D_ + dc;
      s16x8 v0 = *(const s16x8*)(src);
      s16x8 v1 = *(const s16x8*)(src + 8);
#pragma unroll
      for (int j = 0; j < 8; ++j) Vt[dc + j][kvr] = v0[j];
#pragma unroll
      for (int j = 0; j < 8; ++j) Vt[dc + 8 + j][kvr] = v1[j];
    }
    __syncthreads();

    // QK^T for this wave's 32 q-rows x 64 kv
    f32x4 sacc[2][4] = {};
#pragma unroll
    for (int nf = 0; nf < 4; ++nf) {
#pragma unroll
      for (int ks = 0; ks < 2; ++ks) {
        s16x8 kf = *(const s16x8*)(Kbase + (size_t)(kv0 + nf * 16 + l15) * D_ +
                                   ks * 32 + l4 * 8);
#pragma unroll
        for (int mf = 0; mf < 2; ++mf)
          sacc[mf][nf] = __builtin_amdgcn_mfma_f32_16x16x32_bf16(qf[mf][ks], kf,
                                                                 sacc[mf][nf], 0, 0, 0);
      }
    }

    // online softmax (+mask, +gp weighting into Pl)
#pragma unroll
    for (int mf = 0; mf < 2; ++mf) {
#pragma unroll
      for (int r = 0; r < 4; ++r) {
        int qrow = q0 + wq + mf * 16 + l4 * 4 + r;
        const int* mrow = mask + ((size_t)b * S_ + qrow) * S_ + kv0;
        const float* gprow = gp + ((size_t)b * S_ + qrow) * S_ + kv0;
        float lg[4];
        float tmax = -INFINITY;
#pragma unroll
        for (int nf = 0; nf < 4; ++nf) {
          int kvi = nf * 16 + l15;
          float v = sacc[mf][nf][r] * 0.125f;
          v += mrow[kvi] ? 0.f : -1e9f;
          lg[nf] = v;
          tmax = fmaxf(tmax, v);
        }
#pragma unroll
        for (int off = 8; off; off >>= 1)
          tmax = fmaxf(tmax, __shfl_xor(tmax, off));
        float mnew = fmaxf(mrun[mf][r], tmax);
        float f = __expf(mrun[mf][r] - mnew);
        mrun[mf][r] = mnew;
        float psum = 0.f;
#pragma unroll
        for (int nf = 0; nf < 4; ++nf) {
          int kvi = nf * 16 + l15;
          float p = __expf(lg[nf] - mnew);
          psum += p;
          float w = p * gprow[kvi];
          Pl[wave][mf * 16 + l4 * 4 + r][kvi] = f2bf(w);
        }
#pragma unroll
        for (int off = 8; off; off >>= 1)
          psum += __shfl_xor(psum, off);
        lrun[mf][r] = lrun[mf][r] * f + psum;
#pragma unroll
        for (int df = 0; df < 4; ++df) oacc[mf][df][r] *= f;
      }
    }

    // PV
#pragma unroll
    for (int ks = 0; ks < 2; ++ks) {
      s16x8 pa[2];
#pragma unroll
      for (int mf = 0; mf < 2; ++mf)
        pa[mf] = *(const s16x8*)&Pl[wave][mf * 16 + l15][ks * 32 + l4 * 8];
#pragma unroll
      for (int df = 0; df < 4; ++df) {
        s16x8 vb = *(const s16x8*)&Vt[df * 16 + l15][ks * 32 + l4 * 8];
#pragma unroll
        for (int mf = 0; mf < 2; ++mf)
          oacc[mf][df] = __builtin_amdgcn_mfma_f32_16x16x32_bf16(pa[mf], vb,
                                                                 oacc[mf][df], 0, 0, 0);
      }
    }
  }

#pragma unroll
  for (int mf = 0; mf < 2; ++mf) {
#pragma unroll
    for (int r = 0; r < 4; ++r) {
      int qrow = q0 + wq + mf * 16 + l4 * 4 + r;
      float inv = 1.f / lrun[mf][r];
#pragma unroll
      for (int df = 0; df < 4; ++df)
        ctx[((size_t)(b * S_ + qrow)) * D_ + h * DH + df * 16 + l15] =
            f2bf(oacc[mf][df][r] * inv);
    }
  }
}

extern "C" void kernel_launch(void* const* d_in, const int* in_sizes, int n_in,
                              void* d_out, int out_size, void* d_ws, size_t ws_size,
                              hipStream_t stream) {
  const float* query = (const float*)d_in[0];
  const float* key_in = (const float*)d_in[1];
  const float* value = (const float*)d_in[2];
  const float* group_prob = (const float*)d_in[3];
  const int* mask = (const int*)d_in[4];
  const float* wq_k = (const float*)d_in[5];
  const float* wq_b = (const float*)d_in[6];
  const float* wk_k = (const float*)d_in[7];
  const float* wk_b = (const float*)d_in[8];
  const float* wv_k = (const float*)d_in[9];
  const float* wv_b = (const float*)d_in[10];
  const float* wo_k = (const float*)d_in[11];
  const float* wo_b = (const float*)d_in[12];
  float* out = (float*)d_out;

  short* ws = (short*)d_ws;
  const size_t NT = (size_t)B_ * S_ * D_;  // 4M elems
  short* qbf = ws;
  short* kbf = qbf + NT;
  short* vbf = kbf + NT;
  short* wqt = vbf + NT;
  short* wkt = wqt + (size_t)D_ * D_;
  short* wvt = wkt + (size_t)D_ * D_;
  short* wot = wvt + (size_t)D_ * D_;
  short* qp = wot + (size_t)D_ * D_;
  short* kp = qp + NT;
  short* vp = kp + NT;
  short* ctx = vp + NT;

  int nblk = (int)(NT / 4 / 256);
  cvt_f32_bf16<<<nblk, 256, 0, stream>>>(query, qbf, (int)NT);
  cvt_f32_bf16<<<nblk, 256, 0, stream>>>(key_in, kbf, (int)NT);
  cvt_f32_bf16<<<nblk, 256, 0, stream>>>(value, vbf, (int)NT);

  dim3 tb(32, 8);
  dim3 tg(D_ / 32, D_ / 32);
  transpose_cvt<<<tg, tb, 0, stream>>>(wq_k, wqt);
  transpose_cvt<<<tg, tb, 0, stream>>>(wk_k, wkt);
  transpose_cvt<<<tg, tb, 0, stream>>>(wv_k, wvt);
  transpose_cvt<<<tg, tb, 0, stream>>>(wo_k, wot);

  int M = B_ * S_;
  int gblocks = (M / BM) * (D_ / BN);
  gemm_bt<<<gblocks, 256, 0, stream>>>(qbf, wqt, wq_b, qp, M, D_, D_, 0);
  gemm_bt<<<gblocks, 256, 0, stream>>>(kbf, wkt, wk_b, kp, M, D_, D_, 0);
  gemm_bt<<<gblocks, 256, 0, stream>>>(vbf, wvt, wv_b, vp, M, D_, D_, 0);

  dim3 ag(S_ / QB, B_ * H_);
  attn_fused<<<ag, 256, 0, stream>>>(qp, kp, vp, mask, group_prob, ctx);

  gemm_bt<<<gblocks, 256, 0, stream>>>(ctx, wot, wo_b, out, M, D_, D_, 1);
}

// Round 3
// 350.803 us; speedup vs baseline: 1.4873x; 1.4873x over previous
//
#include <hip/hip_runtime.h>
#include <hip/hip_bf16.h>
#include <stdint.h>

#define B_ 2
#define S_ 2048
#define D_ 1024
#define H_ 16
#define DH 64

typedef __attribute__((ext_vector_type(4))) float f32x4;
typedef __attribute__((ext_vector_type(8))) short s16x8;
typedef __attribute__((ext_vector_type(4))) short s16x4;

__device__ inline short f2bf(float f) {
  union { float f; unsigned u; } v; v.f = f;
  unsigned r = (v.u + 0x7fffu + ((v.u >> 16) & 1u)) >> 16;
  return (short)r;
}

__device__ inline float bf2f(unsigned short b) {
  union { unsigned u; float f; } v; v.u = ((unsigned)b) << 16;
  return v.f;
}

__global__ __launch_bounds__(256) void cvt_f32_bf16(const float* __restrict__ in,
                                                    short* __restrict__ out, int n) {
  int i = (blockIdx.x * 256 + threadIdx.x) * 4;
  if (i < n) {
    float4 v = *(const float4*)(in + i);
    s16x4 o;
    o.x = f2bf(v.x); o.y = f2bf(v.y); o.z = f2bf(v.z); o.w = f2bf(v.w);
    *(s16x4*)(out + i) = o;
  }
}

// mgp = mask ? max(bf16(gp), tiny) : 0   (bits==0 <=> masked)
__global__ __launch_bounds__(256) void fuse_mgp(const int* __restrict__ mask,
                                                const float* __restrict__ gp,
                                                short* __restrict__ mgp, int n) {
  int i = (blockIdx.x * 256 + threadIdx.x) * 4;
  if (i < n) {
    int4 m = *(const int4*)(mask + i);
    float4 g = *(const float4*)(gp + i);
    short b0 = f2bf(g.x); if (!b0) b0 = (short)0x0080;
    short b1 = f2bf(g.y); if (!b1) b1 = (short)0x0080;
    short b2 = f2bf(g.z); if (!b2) b2 = (short)0x0080;
    short b3 = f2bf(g.w); if (!b3) b3 = (short)0x0080;
    s16x4 o;
    o.x = m.x ? b0 : 0;
    o.y = m.y ? b1 : 0;
    o.z = m.z ? b2 : 0;
    o.w = m.w ? b3 : 0;
    *(s16x4*)(mgp + i) = o;
  }
}

// out[n][k] = (bf16) in[k][n], square D_ x D_
__global__ __launch_bounds__(256) void transpose_cvt(const float* __restrict__ in,
                                                     short* __restrict__ out) {
  __shared__ float tile[32][33];
  int bx = blockIdx.x, by = blockIdx.y;
  int x = bx * 32 + threadIdx.x;
#pragma unroll
  for (int i = 0; i < 32; i += 8) {
    int y = by * 32 + threadIdx.y + i;
    tile[threadIdx.y + i][threadIdx.x] = in[(size_t)y * D_ + x];
  }
  __syncthreads();
  int ox = by * 32 + threadIdx.x;
#pragma unroll
  for (int i = 0; i < 32; i += 8) {
    int oy = bx * 32 + threadIdx.y + i;
    out[(size_t)oy * D_ + ox] = f2bf(tile[threadIdx.x][threadIdx.y + i]);
  }
}

__device__ inline void gload_lds16(const void* g, void* l) {
  __builtin_amdgcn_global_load_lds(
      (const __attribute__((address_space(1))) unsigned*)g,
      (__attribute__((address_space(3))) unsigned*)l, 16, 0, 0);
}

#define BM 128
#define BN 128
#define BK 32

// C[M][N] = A[M][K] * Bt[N][K]^T + bias ; A,Bt bf16 ; C bf16 or f32
__global__ __launch_bounds__(256) void gemm_bt(const short* __restrict__ A,
                                               const short* __restrict__ Bt,
                                               const float* __restrict__ bias,
                                               void* __restrict__ C,
                                               int M, int N, int K, int f32out) {
  __shared__ __align__(16) short As[BM * BK];
  __shared__ __align__(16) short Bs[BN * BK];
  int tid = threadIdx.x;
  int lane = tid & 63, wave = tid >> 6;
  int l15 = lane & 15, l4 = lane >> 4;
  int ntn = N / BN;
  int bm = blockIdx.x / ntn, bn = blockIdx.x % ntn;
  int row0 = bm * BM, col0 = bn * BN;
  int wm = (wave >> 1) * 64, wn = (wave & 1) * 64;

  f32x4 acc[4][4] = {};

  for (int k0 = 0; k0 < K; k0 += BK) {
    __syncthreads();
#pragma unroll
    for (int it = 0; it < 2; ++it) {
      int ch = it * 256 + tid;
      int r = ch >> 2, c = (ch & 3) * 8;
      int ldsbase = (it * 256 + wave * 64) * 8;  // elems; HW adds lane*16B
      gload_lds16(A + (size_t)(row0 + r) * K + k0 + c, &As[ldsbase]);
      gload_lds16(Bt + (size_t)(col0 + r) * K + k0 + c, &Bs[ldsbase]);
    }
    __syncthreads();
    s16x8 af[4], bf[4];
#pragma unroll
    for (int mf = 0; mf < 4; ++mf)
      af[mf] = *(const s16x8*)&As[(wm + mf * 16 + l15) * BK + l4 * 8];
#pragma unroll
    for (int nf = 0; nf < 4; ++nf)
      bf[nf] = *(const s16x8*)&Bs[(wn + nf * 16 + l15) * BK + l4 * 8];
#pragma unroll
    for (int mf = 0; mf < 4; ++mf)
#pragma unroll
      for (int nf = 0; nf < 4; ++nf)
        acc[mf][nf] = __builtin_amdgcn_mfma_f32_16x16x32_bf16(af[mf], bf[nf],
                                                              acc[mf][nf], 0, 0, 0);
  }

#pragma unroll
  for (int nf = 0; nf < 4; ++nf) {
    int gcol = col0 + wn + nf * 16 + l15;
    float bv = bias[gcol];
#pragma unroll
    for (int mf = 0; mf < 4; ++mf) {
#pragma unroll
      for (int r = 0; r < 4; ++r) {
        int grow = row0 + wm + mf * 16 + l4 * 4 + r;
        float v = acc[mf][nf][r] + bv;
        if (f32out)
          ((float*)C)[(size_t)grow * N + gcol] = v;
        else
          ((short*)C)[(size_t)grow * N + gcol] = f2bf(v);
      }
    }
  }
}

#define QB 64
#define NB 64

// q,k,v bf16 (B,S,H*DH); mgp bf16 (B,S,S) (0 bits == masked); ctx bf16 out.
// Pipelined flash attention: K/mgp double-buffered LDS via global_load_lds,
// V reg-prefetched one tile ahead; P reuses the consumed mgp buffer (swizzled).
__global__ __launch_bounds__(256) void attn_fused(const short* __restrict__ Qp,
                                                  const short* __restrict__ Kp,
                                                  const short* __restrict__ Vp,
                                                  const short* __restrict__ MGP,
                                                  short* __restrict__ ctx) {
  __shared__ __align__(16) short Ks[2][64 * 64];  // XOR-swizzled 16B chunks
  __shared__ __align__(16) short Ms[2][64 * 64];  // swizzled; reused for P
  __shared__ __align__(16) short Vt[DH][72];      // [d][kv], padded

  int tid = threadIdx.x, lane = tid & 63, wave = tid >> 6;
  int l15 = lane & 15, l4 = lane >> 4;
  int q0 = blockIdx.x * QB;
  int bh = blockIdx.y;
  int b = bh >> 4, h = bh & 15;
  int wq = wave * 16;

  const short* Qbase = Qp + (size_t)b * S_ * D_ + (size_t)h * DH;
  const short* Kbase = Kp + (size_t)b * S_ * D_ + (size_t)h * DH;
  const short* Vbase = Vp + (size_t)b * S_ * D_ + (size_t)h * DH;
  const short* Mbase = MGP + (size_t)b * S_ * S_ + (size_t)q0 * S_;

  // staging geometry: 512 chunks of 16B per 64x64 tile; chunk i -> row i>>3,
  // swizzled slot p=i&7 holds source chunk c = p ^ (row&7)
  int i0 = tid, i1 = 256 + tid;
  int r0 = i0 >> 3, c0 = (i0 & 7) ^ (r0 & 7);
  int r1 = i1 >> 3, c1 = (i1 & 7) ^ (r1 & 7);
  int ldsA = (wave * 64) * 8;         // elem offset of wave's chunk base, it=0
  int ldsB = (256 + wave * 64) * 8;   // it=1
  int kvr = tid >> 2, dc = (tid & 3) * 16;

  s16x8 qf[2];
#pragma unroll
  for (int ks = 0; ks < 2; ++ks)
    qf[ks] = *(const s16x8*)(Qbase + (size_t)(q0 + wq + l15) * D_ + ks * 32 + l4 * 8);

  float mrun[4], lrun[4];
  f32x4 oacc[4] = {};
#pragma unroll
  for (int r = 0; r < 4; ++r) { mrun[r] = -INFINITY; lrun[r] = 0.f; }

  // prologue: V regs + staged K/mgp for tile 0
  s16x8 va = *(const s16x8*)(Vbase + (size_t)kvr * D_ + dc);
  s16x8 vb = *(const s16x8*)(Vbase + (size_t)kvr * D_ + dc + 8);
  gload_lds16(Kbase + (size_t)r0 * D_ + c0 * 8, &Ks[0][ldsA]);
  gload_lds16(Kbase + (size_t)r1 * D_ + c1 * 8, &Ks[0][ldsB]);
  gload_lds16(Mbase + (size_t)r0 * S_ + c0 * 8, &Ms[0][ldsA]);
  gload_lds16(Mbase + (size_t)r1 * S_ + c1 * 8, &Ms[0][ldsB]);

  for (int t = 0; t < S_ / NB; ++t) {
    int buf = t & 1, nxt = buf ^ 1;
    int kvn = ((t + 1) & (S_ / NB - 1)) * NB;

    // 1. commit prefetched V regs to LDS (compiler inserts vmcnt wait)
#pragma unroll
    for (int j = 0; j < 8; ++j) Vt[dc + j][kvr] = va[j];
#pragma unroll
    for (int j = 0; j < 8; ++j) Vt[dc + 8 + j][kvr] = vb[j];

    // 2. prefetch next V into regs
    va = *(const s16x8*)(Vbase + (size_t)(kvn + kvr) * D_ + dc);
    vb = *(const s16x8*)(Vbase + (size_t)(kvn + kvr) * D_ + dc + 8);

    // 3. stage next K/mgp tiles (stay in flight across the barrier)
    gload_lds16(Kbase + (size_t)(kvn + r0) * D_ + c0 * 8, &Ks[nxt][ldsA]);
    gload_lds16(Kbase + (size_t)(kvn + r1) * D_ + c1 * 8, &Ks[nxt][ldsB]);
    gload_lds16(Mbase + (size_t)r0 * S_ + kvn + c0 * 8, &Ms[nxt][ldsA]);
    gload_lds16(Mbase + (size_t)r1 * S_ + kvn + c1 * 8, &Ms[nxt][ldsB]);

    // 4. wait: current-tile staged K/mgp done (6 newer ops in flight), V writes
    asm volatile("s_waitcnt vmcnt(6) lgkmcnt(0)" ::: "memory");
    __builtin_amdgcn_s_barrier();
    __builtin_amdgcn_sched_barrier(0);

    // 5. QK^T  (swizzled ds_read_b128: conflict-free)
    f32x4 sacc[4] = {};
#pragma unroll
    for (int nf = 0; nf < 4; ++nf) {
      int R = nf * 16 + l15;
#pragma unroll
      for (int ks = 0; ks < 2; ++ks) {
        s16x8 kf = *(const s16x8*)&Ks[buf][R * 64 + (((ks * 4 + l4) ^ (l15 & 7)) * 8)];
        sacc[nf] = __builtin_amdgcn_mfma_f32_16x16x32_bf16(qf[ks], kf, sacc[nf], 0, 0, 0);
      }
    }

    // 6. online softmax; P*gp written (bf16, swizzled) into consumed Ms[buf]
#pragma unroll
    for (int r = 0; r < 4; ++r) {
      int ql = wq + l4 * 4 + r;
      unsigned short* mrow = (unsigned short*)&Ms[buf][ql * 64];
      int q7 = ql & 7;
      float lg[4], gv[4];
      float tmax = -1e30f;
#pragma unroll
      for (int nf = 0; nf < 4; ++nf) {
        int kvi = nf * 16 + l15;
        unsigned short mg = mrow[((kvi >> 3) ^ q7) * 8 + (kvi & 7)];
        gv[nf] = bf2f(mg);
        float s = sacc[nf][r] * 0.125f;
        lg[nf] = mg ? s : -1e9f;
        tmax = fmaxf(tmax, lg[nf]);
      }
#pragma unroll
      for (int off = 8; off; off >>= 1)
        tmax = fmaxf(tmax, __shfl_xor(tmax, off));
      float mnew = fmaxf(mrun[r], tmax);
      float f = __expf(mrun[r] - mnew);
      mrun[r] = mnew;
      float w[4], psum = 0.f;
#pragma unroll
      for (int nf = 0; nf < 4; ++nf) {
        float p = __expf(lg[nf] - mnew);
        psum += p;
        w[nf] = p * gv[nf];
      }
#pragma unroll
      for (int off = 8; off; off >>= 1)
        psum += __shfl_xor(psum, off);
      lrun[r] = lrun[r] * f + psum;
#pragma unroll
      for (int df = 0; df < 4; ++df) oacc[df][r] *= f;
      // write phase (reads of this row, all lanes, issued above in order)
#pragma unroll
      for (int nf = 0; nf < 4; ++nf) {
        int kvi = nf * 16 + l15;
        mrow[((kvi >> 3) ^ q7) * 8 + (kvi & 7)] = (unsigned short)f2bf(w[nf]);
      }
    }

    // 7. PV
#pragma unroll
    for (int ks = 0; ks < 2; ++ks) {
      s16x8 pa = *(const s16x8*)&Ms[buf][(wq + l15) * 64 + (((ks * 4 + l4) ^ (l15 & 7)) * 8)];
#pragma unroll
      for (int df = 0; df < 4; ++df) {
        s16x8 vf = *(const s16x8*)&Vt[df * 16 + l15][ks * 32 + l4 * 8];
        oacc[df] = __builtin_amdgcn_mfma_f32_16x16x32_bf16(pa, vf, oacc[df], 0, 0, 0);
      }
    }

    asm volatile("s_waitcnt lgkmcnt(0)" ::: "memory");
    __builtin_amdgcn_s_barrier();
  }

#pragma unroll
  for (int r = 0; r < 4; ++r) {
    int qrow = q0 + wq + l4 * 4 + r;
    float inv = 1.f / lrun[r];
#pragma unroll
    for (int df = 0; df < 4; ++df)
      ctx[((size_t)(b * S_ + qrow)) * D_ + h * DH + df * 16 + l15] =
          f2bf(oacc[df][r] * inv);
  }
}

extern "C" void kernel_launch(void* const* d_in, const int* in_sizes, int n_in,
                              void* d_out, int out_size, void* d_ws, size_t ws_size,
                              hipStream_t stream) {
  const float* query = (const float*)d_in[0];
  const float* key_in = (const float*)d_in[1];
  const float* value = (const float*)d_in[2];
  const float* group_prob = (const float*)d_in[3];
  const int* mask = (const int*)d_in[4];
  const float* wq_k = (const float*)d_in[5];
  const float* wq_b = (const float*)d_in[6];
  const float* wk_k = (const float*)d_in[7];
  const float* wk_b = (const float*)d_in[8];
  const float* wv_k = (const float*)d_in[9];
  const float* wv_b = (const float*)d_in[10];
  const float* wo_k = (const float*)d_in[11];
  const float* wo_b = (const float*)d_in[12];
  float* out = (float*)d_out;

  short* ws = (short*)d_ws;
  const size_t NT = (size_t)B_ * S_ * D_;  // 4.19M elems
  short* qbf = ws;
  short* kbf = qbf + NT;
  short* vbf = kbf + NT;
  short* wqt = vbf + NT;
  short* wkt = wqt + (size_t)D_ * D_;
  short* wvt = wkt + (size_t)D_ * D_;
  short* wot = wvt + (size_t)D_ * D_;
  short* qp = wot + (size_t)D_ * D_;
  short* kp = qp + NT;
  short* vp = kp + NT;
  short* ctx = vp + NT;
  short* mgp = ws;  // reuses qbf+kbf exactly (B*S*S == 2*NT); dead after GEMMs

  int nblk = (int)(NT / 4 / 256);
  cvt_f32_bf16<<<nblk, 256, 0, stream>>>(query, qbf, (int)NT);
  cvt_f32_bf16<<<nblk, 256, 0, stream>>>(key_in, kbf, (int)NT);
  cvt_f32_bf16<<<nblk, 256, 0, stream>>>(value, vbf, (int)NT);

  dim3 tb(32, 8);
  dim3 tg(D_ / 32, D_ / 32);
  transpose_cvt<<<tg, tb, 0, stream>>>(wq_k, wqt);
  transpose_cvt<<<tg, tb, 0, stream>>>(wk_k, wkt);
  transpose_cvt<<<tg, tb, 0, stream>>>(wv_k, wvt);
  transpose_cvt<<<tg, tb, 0, stream>>>(wo_k, wot);

  int M = B_ * S_;
  int gblocks = (M / BM) * (D_ / BN);
  gemm_bt<<<gblocks, 256, 0, stream>>>(qbf, wqt, wq_b, qp, M, D_, D_, 0);
  gemm_bt<<<gblocks, 256, 0, stream>>>(kbf, wkt, wk_b, kp, M, D_, D_, 0);
  gemm_bt<<<gblocks, 256, 0, stream>>>(vbf, wvt, wv_b, vp, M, D_, D_, 0);

  // mask*gp fusion AFTER projections (overwrites qbf/kbf region)
  int nmg = B_ * S_ * S_;
  fuse_mgp<<<nmg / 4 / 256, 256, 0, stream>>>(mask, group_prob, mgp, nmg);

  dim3 ag(S_ / QB, B_ * H_);
  attn_fused<<<ag, 256, 0, stream>>>(qp, kp, vp, mgp, ctx);

  gemm_bt<<<gblocks, 256, 0, stream>>>(ctx, wot, wo_b, out, M, D_, D_, 1);
}

// Round 4
// 259.312 us; speedup vs baseline: 2.0121x; 1.3528x over previous
//
#include <hip/hip_runtime.h>
#include <hip/hip_bf16.h>
#include <stdint.h>

#define B_ 2
#define S_ 2048
#define D_ 1024
#define H_ 16
#define DH 64

typedef __attribute__((ext_vector_type(4))) float f32x4;
typedef __attribute__((ext_vector_type(8))) short s16x8;
typedef __attribute__((ext_vector_type(4))) short s16x4;

__device__ inline short f2bf(float f) {
  union { float f; unsigned u; } v; v.f = f;
  unsigned r = (v.u + 0x7fffu + ((v.u >> 16) & 1u)) >> 16;
  return (short)r;
}

__device__ inline float bfbits_lo(unsigned u) {
  union { unsigned x; float f; } v; v.x = u << 16; return v.f;
}
__device__ inline float bfbits_hi(unsigned u) {
  union { unsigned x; float f; } v; v.x = u & 0xffff0000u; return v.f;
}

__device__ inline float exp2v(float x) {
  float r; asm("v_exp_f32 %0, %1" : "=v"(r) : "v"(x)); return r;
}
__device__ inline unsigned cvtpk(float a, float b) {
  unsigned r; asm("v_cvt_pk_bf16_f32 %0, %1, %2" : "=v"(r) : "v"(a), "v"(b));
  return r;
}

__global__ __launch_bounds__(256) void cvt_f32_bf16(const float* __restrict__ in,
                                                    short* __restrict__ out, int n) {
  int i = (blockIdx.x * 256 + threadIdx.x) * 4;
  if (i < n) {
    float4 v = *(const float4*)(in + i);
    s16x4 o;
    o.x = f2bf(v.x); o.y = f2bf(v.y); o.z = f2bf(v.z); o.w = f2bf(v.w);
    *(s16x4*)(out + i) = o;
  }
}

// mgp = mask ? max(bf16(gp), tiny) : 0   (bits==0 <=> masked)
__global__ __launch_bounds__(256) void fuse_mgp(const int* __restrict__ mask,
                                                const float* __restrict__ gp,
                                                short* __restrict__ mgp, int n) {
  int i = (blockIdx.x * 256 + threadIdx.x) * 4;
  if (i < n) {
    int4 m = *(const int4*)(mask + i);
    float4 g = *(const float4*)(gp + i);
    short b0 = f2bf(g.x); if (!b0) b0 = (short)0x0080;
    short b1 = f2bf(g.y); if (!b1) b1 = (short)0x0080;
    short b2 = f2bf(g.z); if (!b2) b2 = (short)0x0080;
    short b3 = f2bf(g.w); if (!b3) b3 = (short)0x0080;
    s16x4 o;
    o.x = m.x ? b0 : 0;
    o.y = m.y ? b1 : 0;
    o.z = m.z ? b2 : 0;
    o.w = m.w ? b3 : 0;
    *(s16x4*)(mgp + i) = o;
  }
}

// out[n][k] = (bf16) in[k][n], square D_ x D_
__global__ __launch_bounds__(256) void transpose_cvt(const float* __restrict__ in,
                                                     short* __restrict__ out) {
  __shared__ float tile[32][33];
  int bx = blockIdx.x, by = blockIdx.y;
  int x = bx * 32 + threadIdx.x;
#pragma unroll
  for (int i = 0; i < 32; i += 8) {
    int y = by * 32 + threadIdx.y + i;
    tile[threadIdx.y + i][threadIdx.x] = in[(size_t)y * D_ + x];
  }
  __syncthreads();
  int ox = by * 32 + threadIdx.x;
#pragma unroll
  for (int i = 0; i < 32; i += 8) {
    int oy = bx * 32 + threadIdx.y + i;
    out[(size_t)oy * D_ + ox] = f2bf(tile[threadIdx.x][threadIdx.y + i]);
  }
}

__device__ inline void gload_lds16(const void* g, void* l) {
  __builtin_amdgcn_global_load_lds(
      (const __attribute__((address_space(1))) unsigned*)g,
      (__attribute__((address_space(3))) unsigned*)l, 16, 0, 0);
}

#define BM 128
#define BN 128
#define BK 32

// C[M][N] = (A[M][K] * Bt[N][K]^T + bias) * oscale ; A,Bt bf16 ; C bf16 or f32
__global__ __launch_bounds__(256) void gemm_bt(const short* __restrict__ A,
                                               const short* __restrict__ Bt,
                                               const float* __restrict__ bias,
                                               void* __restrict__ C,
                                               int M, int N, int K, int f32out,
                                               float oscale) {
  __shared__ __align__(16) short As[BM * BK];
  __shared__ __align__(16) short Bs[BN * BK];
  int tid = threadIdx.x;
  int lane = tid & 63, wave = tid >> 6;
  int l15 = lane & 15, l4 = lane >> 4;
  int ntn = N / BN;
  int bm = blockIdx.x / ntn, bn = blockIdx.x % ntn;
  int row0 = bm * BM, col0 = bn * BN;
  int wm = (wave >> 1) * 64, wn = (wave & 1) * 64;

  f32x4 acc[4][4] = {};

  for (int k0 = 0; k0 < K; k0 += BK) {
    __syncthreads();
#pragma unroll
    for (int it = 0; it < 2; ++it) {
      int ch = it * 256 + tid;
      int r = ch >> 2, c = (ch & 3) * 8;
      int ldsbase = (it * 256 + wave * 64) * 8;  // elems; HW adds lane*16B
      gload_lds16(A + (size_t)(row0 + r) * K + k0 + c, &As[ldsbase]);
      gload_lds16(Bt + (size_t)(col0 + r) * K + k0 + c, &Bs[ldsbase]);
    }
    __syncthreads();
    s16x8 af[4], bf[4];
#pragma unroll
    for (int mf = 0; mf < 4; ++mf)
      af[mf] = *(const s16x8*)&As[(wm + mf * 16 + l15) * BK + l4 * 8];
#pragma unroll
    for (int nf = 0; nf < 4; ++nf)
      bf[nf] = *(const s16x8*)&Bs[(wn + nf * 16 + l15) * BK + l4 * 8];
#pragma unroll
    for (int mf = 0; mf < 4; ++mf)
#pragma unroll
      for (int nf = 0; nf < 4; ++nf)
        acc[mf][nf] = __builtin_amdgcn_mfma_f32_16x16x32_bf16(af[mf], bf[nf],
                                                              acc[mf][nf], 0, 0, 0);
  }

#pragma unroll
  for (int nf = 0; nf < 4; ++nf) {
    int gcol = col0 + wn + nf * 16 + l15;
    float bv = bias[gcol];
#pragma unroll
    for (int mf = 0; mf < 4; ++mf) {
#pragma unroll
      for (int r = 0; r < 4; ++r) {
        int grow = row0 + wm + mf * 16 + l4 * 4 + r;
        float v = (acc[mf][nf][r] + bv) * oscale;
        if (f32out)
          ((float*)C)[(size_t)grow * N + gcol] = v;
        else
          ((short*)C)[(size_t)grow * N + gcol] = f2bf(v);
      }
    }
  }
}

#define QB 64
#define NB 64
#define M0_SHIFT 12.0f

// q (pre-scaled by 0.125*log2e), k, v bf16 (B,S,H*DH); mgp bf16 (B,S,S)
// (bits==0 <=> masked); ctx bf16 out. Swapped-operand flash attention:
// QK^T computed transposed so softmax data motion is b64/b128 vector LDS.
__global__ __launch_bounds__(256) void attn_fused(const short* __restrict__ Qp,
                                                  const short* __restrict__ Kp,
                                                  const short* __restrict__ Vp,
                                                  const short* __restrict__ MGP,
                                                  short* __restrict__ ctx) {
  __shared__ __align__(16) short Ks[2][64 * 64];  // K tiles, 16B-chunk swizzled
  __shared__ __align__(16) short Ms[2][64 * 64];  // mgp tiles (reused for P)
  __shared__ __align__(16) short Vt[DH * 72];     // V^T [d][kv^f(d)], pad 72

  int tid = threadIdx.x, lane = tid & 63, wave = tid >> 6;
  int l15 = lane & 15, l4 = lane >> 4;
  int q0 = blockIdx.x * QB;
  int bh = blockIdx.y;
  int b = bh >> 4, h = bh & 15;
  int wq = wave * 16;

  const short* Qbase = Qp + (size_t)b * S_ * D_ + (size_t)h * DH;
  const short* Kbase = Kp + (size_t)b * S_ * D_ + (size_t)h * DH;
  const short* Vbase = Vp + (size_t)b * S_ * D_ + (size_t)h * DH;
  const short* Mbase = MGP + (size_t)b * S_ * S_ + (size_t)q0 * S_;

  // staging geometry: 512 chunks of 16B per 64x64 tile; LDS slot p of row r
  // holds source chunk p ^ (r&7)
  int i0 = tid, i1 = 256 + tid;
  int r0 = i0 >> 3, c0 = (i0 & 7) ^ (r0 & 7);
  int r1 = i1 >> 3, c1 = (i1 & 7) ^ (r1 & 7);
  int ldsA = (wave * 64) * 8;        // elem offset of wave's chunk base, it=0
  int ldsB = (256 + wave * 64) * 8;  // it=1
  int kvr = tid >> 2, dc = (tid & 3) * 16, c2 = tid & 3;

  s16x8 qf[2];
#pragma unroll
  for (int ks = 0; ks < 2; ++ks)
    qf[ks] = *(const s16x8*)(Qbase + (size_t)(q0 + wq + l15) * D_ + ks * 32 + l4 * 8);

  float lsum = 0.f;
  f32x4 oacc[4] = {};

  // prologue: V regs + staged K/mgp for tile 0
  s16x8 va = *(const s16x8*)(Vbase + (size_t)kvr * D_ + dc);
  s16x8 vb = *(const s16x8*)(Vbase + (size_t)kvr * D_ + dc + 8);
  gload_lds16(Kbase + (size_t)r0 * D_ + c0 * 8, &Ks[0][ldsA]);
  gload_lds16(Kbase + (size_t)r1 * D_ + c1 * 8, &Ks[0][ldsB]);
  gload_lds16(Mbase + (size_t)r0 * S_ + c0 * 8, &Ms[0][ldsA]);
  gload_lds16(Mbase + (size_t)r1 * S_ + c1 * 8, &Ms[0][ldsB]);

  int ql = wq + l15;
  int rowoff = ql * 64;
  int q7 = l15 & 7;
  int q7l = q7 << 1;

  for (int t = 0; t < S_ / NB; ++t) {
    int buf = t & 1, nxt = buf ^ 1;
    int kvn = ((t + 1) & (S_ / NB - 1)) * NB;

    // 1. commit prefetched V regs to Vt (column-swizzled: conflict-free)
#pragma unroll
    for (int j = 0; j < 8; ++j) {
      int f = ((j ^ c2) & 7) * 8;
      Vt[(dc + j) * 72 + (kvr ^ f)] = va[j];
      Vt[(dc + 8 + j) * 72 + (kvr ^ f)] = vb[j];
    }

    // 2. prefetch next V into regs
    va = *(const s16x8*)(Vbase + (size_t)(kvn + kvr) * D_ + dc);
    vb = *(const s16x8*)(Vbase + (size_t)(kvn + kvr) * D_ + dc + 8);

    // 3. stage next K/mgp tiles (stay in flight across the barrier)
    gload_lds16(Kbase + (size_t)(kvn + r0) * D_ + c0 * 8, &Ks[nxt][ldsA]);
    gload_lds16(Kbase + (size_t)(kvn + r1) * D_ + c1 * 8, &Ks[nxt][ldsB]);
    gload_lds16(Mbase + (size_t)r0 * S_ + kvn + c0 * 8, &Ms[nxt][ldsA]);
    gload_lds16(Mbase + (size_t)r1 * S_ + kvn + c1 * 8, &Ms[nxt][ldsB]);

    // 4. wait: current staged K/mgp done (6 newer ops in flight), V writes done
    asm volatile("s_waitcnt vmcnt(6) lgkmcnt(0)" ::: "memory");
    __builtin_amdgcn_s_barrier();
    __builtin_amdgcn_sched_barrier(0);

    // 5. QK^T swapped: sacc[nf] = S^T[kv = nf*16 + l4*4 + r][q = wq + l15]
    f32x4 sacc[4] = {};
#pragma unroll
    for (int nf = 0; nf < 4; ++nf) {
      int R = nf * 16 + l15;
#pragma unroll
      for (int ks = 0; ks < 2; ++ks) {
        s16x8 kf = *(const s16x8*)&Ks[buf][R * 64 + (((ks * 4 + l4) ^ q7) * 8)];
        sacc[nf] = __builtin_amdgcn_mfma_f32_16x16x32_bf16(kf, qf[ks], sacc[nf], 0, 0, 0);
      }
    }

    // 6. softmax (no max tracking): p = exp2(s - M0); P*gp back into Ms[buf]
#pragma unroll
    for (int nf = 0; nf < 4; ++nf) {
      int sl = ((nf * 4 + l4) ^ q7l) * 4;
      uint2 g2 = *(const uint2*)&Ms[buf][rowoff + sl];
      float gv0 = bfbits_lo(g2.x), gv1 = bfbits_hi(g2.x);
      float gv2 = bfbits_lo(g2.y), gv3 = bfbits_hi(g2.y);
      float e0 = exp2v(sacc[nf][0] - M0_SHIFT);
      float e1 = exp2v(sacc[nf][1] - M0_SHIFT);
      float e2 = exp2v(sacc[nf][2] - M0_SHIFT);
      float e3 = exp2v(sacc[nf][3] - M0_SHIFT);
      lsum += (gv0 != 0.f) ? e0 : 0.f;
      lsum += (gv1 != 0.f) ? e1 : 0.f;
      lsum += (gv2 != 0.f) ? e2 : 0.f;
      lsum += (gv3 != 0.f) ? e3 : 0.f;
      uint2 wp;
      wp.x = cvtpk(e0 * gv0, e1 * gv1);
      wp.y = cvtpk(e2 * gv2, e3 * gv3);
      *(uint2*)&Ms[buf][rowoff + sl] = wp;
    }

    // 7. PV swapped: oacc[df] = O^T[d = df*16 + l4*4 + r][q = wq + l15]
#pragma unroll
    for (int ks = 0; ks < 2; ++ks) {
      s16x8 pa = *(const s16x8*)&Ms[buf][rowoff + (((ks * 4 + l4) ^ q7) * 8)];
#pragma unroll
      for (int df = 0; df < 4; ++df) {
        s16x8 vf = *(const s16x8*)&Vt[(df * 16 + l15) * 72 +
                                      ((ks * 32 + l4 * 8) ^ ((q7 ^ df) * 8))];
        oacc[df] = __builtin_amdgcn_mfma_f32_16x16x32_bf16(vf, pa, oacc[df], 0, 0, 0);
      }
    }

    asm volatile("s_waitcnt lgkmcnt(0)" ::: "memory");
    __builtin_amdgcn_s_barrier();
  }

  // epilogue: row-sum reduce across the 4 l4 groups, then store O^T/l
  lsum += __shfl_xor(lsum, 16);
  lsum += __shfl_xor(lsum, 32);
  float inv = 1.f / lsum;
  short* crow = ctx + ((size_t)(b * S_ + q0 + wq + l15)) * D_ + h * DH;
#pragma unroll
  for (int df = 0; df < 4; ++df) {
    uint2 o;
    o.x = cvtpk(oacc[df][0] * inv, oacc[df][1] * inv);
    o.y = cvtpk(oacc[df][2] * inv, oacc[df][3] * inv);
    *(uint2*)(crow + df * 16 + l4 * 4) = o;
  }
}

extern "C" void kernel_launch(void* const* d_in, const int* in_sizes, int n_in,
                              void* d_out, int out_size, void* d_ws, size_t ws_size,
                              hipStream_t stream) {
  const float* query = (const float*)d_in[0];
  const float* key_in = (const float*)d_in[1];
  const float* value = (const float*)d_in[2];
  const float* group_prob = (const float*)d_in[3];
  const int* mask = (const int*)d_in[4];
  const float* wq_k = (const float*)d_in[5];
  const float* wq_b = (const float*)d_in[6];
  const float* wk_k = (const float*)d_in[7];
  const float* wk_b = (const float*)d_in[8];
  const float* wv_k = (const float*)d_in[9];
  const float* wv_b = (const float*)d_in[10];
  const float* wo_k = (const float*)d_in[11];
  const float* wo_b = (const float*)d_in[12];
  float* out = (float*)d_out;

  short* ws = (short*)d_ws;
  const size_t NT = (size_t)B_ * S_ * D_;  // 4.19M elems
  short* qbf = ws;
  short* kbf = qbf + NT;
  short* vbf = kbf + NT;
  short* wqt = vbf + NT;
  short* wkt = wqt + (size_t)D_ * D_;
  short* wvt = wkt + (size_t)D_ * D_;
  short* wot = wvt + (size_t)D_ * D_;
  short* qp = wot + (size_t)D_ * D_;
  short* kp = qp + NT;
  short* vp = kp + NT;
  short* ctx = vp + NT;
  short* mgp = ws;  // reuses qbf+kbf exactly (B*S*S == 2*NT); dead after GEMMs

  int nblk = (int)(NT / 4 / 256);
  cvt_f32_bf16<<<nblk, 256, 0, stream>>>(query, qbf, (int)NT);
  cvt_f32_bf16<<<nblk, 256, 0, stream>>>(key_in, kbf, (int)NT);
  cvt_f32_bf16<<<nblk, 256, 0, stream>>>(value, vbf, (int)NT);

  dim3 tb(32, 8);
  dim3 tg(D_ / 32, D_ / 32);
  transpose_cvt<<<tg, tb, 0, stream>>>(wq_k, wqt);
  transpose_cvt<<<tg, tb, 0, stream>>>(wk_k, wkt);
  transpose_cvt<<<tg, tb, 0, stream>>>(wv_k, wvt);
  transpose_cvt<<<tg, tb, 0, stream>>>(wo_k, wot);

  int M = B_ * S_;
  int gblocks = (M / BM) * (D_ / BN);
  // Q projection pre-scaled by 1/sqrt(dh) * log2(e) (folded softmax scale)
  const float QSCALE = 0.125f * 1.4426950408889634f;
  gemm_bt<<<gblocks, 256, 0, stream>>>(qbf, wqt, wq_b, qp, M, D_, D_, 0, QSCALE);
  gemm_bt<<<gblocks, 256, 0, stream>>>(kbf, wkt, wk_b, kp, M, D_, D_, 0, 1.0f);
  gemm_bt<<<gblocks, 256, 0, stream>>>(vbf, wvt, wv_b, vp, M, D_, D_, 0, 1.0f);

  // mask*gp fusion AFTER projections (overwrites qbf/kbf region)
  int nmg = B_ * S_ * S_;
  fuse_mgp<<<nmg / 4 / 256, 256, 0, stream>>>(mask, group_prob, mgp, nmg);

  dim3 ag(S_ / QB, B_ * H_);
  attn_fused<<<ag, 256, 0, stream>>>(qp, kp, vp, mgp, ctx);

  gemm_bt<<<gblocks, 256, 0, stream>>>(ctx, wot, wo_b, out, M, D_, D_, 1, 1.0f);
}

// Round 5
// 192.616 us; speedup vs baseline: 2.7088x; 1.3463x over previous
//
#include <hip/hip_runtime.h>
#include <hip/hip_bf16.h>
#include <stdint.h>

#define B_ 2
#define S_ 2048
#define D_ 1024
#define H_ 16
#define DH 64

typedef __attribute__((ext_vector_type(4))) float f32x4;
typedef __attribute__((ext_vector_type(8))) short s16x8;
typedef __attribute__((ext_vector_type(4))) short s16x4;

__device__ inline short f2bf(float f) {
  union { float f; unsigned u; } v; v.f = f;
  unsigned r = (v.u + 0x7fffu + ((v.u >> 16) & 1u)) >> 16;
  return (short)r;
}

__device__ inline float bfbits_lo(unsigned u) {
  union { unsigned x; float f; } v; v.x = u << 16; return v.f;
}
__device__ inline float bfbits_hi(unsigned u) {
  union { unsigned x; float f; } v; v.x = u & 0xffff0000u; return v.f;
}

__device__ inline float exp2v(float x) {
  float r; asm("v_exp_f32 %0, %1" : "=v"(r) : "v"(x)); return r;
}
__device__ inline unsigned cvtpk(float a, float b) {
  unsigned r; asm("v_cvt_pk_bf16_f32 %0, %1, %2" : "=v"(r) : "v"(a), "v"(b));
  return r;
}

// 3 tensors f32->bf16 in one launch (blockIdx.y selects)
__global__ __launch_bounds__(256) void cvt3_f32_bf16(const float* __restrict__ a,
                                                     const float* __restrict__ b,
                                                     const float* __restrict__ c,
                                                     short* oa, short* ob, short* oc,
                                                     int n) {
  int z = blockIdx.y;
  const float* in = z == 0 ? a : (z == 1 ? b : c);
  short* out = z == 0 ? oa : (z == 1 ? ob : oc);
  int i = (blockIdx.x * 256 + threadIdx.x) * 4;
  if (i < n) {
    float4 v = *(const float4*)(in + i);
    s16x4 o;
    o.x = f2bf(v.x); o.y = f2bf(v.y); o.z = f2bf(v.z); o.w = f2bf(v.w);
    *(s16x4*)(out + i) = o;
  }
}

// mgp = mask ? max(bf16(gp), tiny) : 0   (bits==0 <=> masked)
__global__ __launch_bounds__(256) void fuse_mgp(const int* __restrict__ mask,
                                                const float* __restrict__ gp,
                                                short* __restrict__ mgp, int n) {
  int i = (blockIdx.x * 256 + threadIdx.x) * 4;
  if (i < n) {
    int4 m = *(const int4*)(mask + i);
    float4 g = *(const float4*)(gp + i);
    short b0 = f2bf(g.x); if (!b0) b0 = (short)0x0080;
    short b1 = f2bf(g.y); if (!b1) b1 = (short)0x0080;
    short b2 = f2bf(g.z); if (!b2) b2 = (short)0x0080;
    short b3 = f2bf(g.w); if (!b3) b3 = (short)0x0080;
    s16x4 o;
    o.x = m.x ? b0 : 0;
    o.y = m.y ? b1 : 0;
    o.z = m.z ? b2 : 0;
    o.w = m.w ? b3 : 0;
    *(s16x4*)(mgp + i) = o;
  }
}

// 4 weight matrices: out[n][k] = (bf16) in[k][n], D_ x D_ (blockIdx.z selects)
__global__ __launch_bounds__(256) void transpose_cvt4(
    const float* __restrict__ i0, const float* __restrict__ i1,
    const float* __restrict__ i2, const float* __restrict__ i3,
    short* o0, short* o1, short* o2, short* o3) {
  int z = blockIdx.z;
  const float* in = z == 0 ? i0 : (z == 1 ? i1 : (z == 2 ? i2 : i3));
  short* out = z == 0 ? o0 : (z == 1 ? o1 : (z == 2 ? o2 : o3));
  __shared__ float tile[32][33];
  int bx = blockIdx.x, by = blockIdx.y;
  int x = bx * 32 + threadIdx.x;
#pragma unroll
  for (int i = 0; i < 32; i += 8) {
    int y = by * 32 + threadIdx.y + i;
    tile[threadIdx.y + i][threadIdx.x] = in[(size_t)y * D_ + x];
  }
  __syncthreads();
  int ox = by * 32 + threadIdx.x;
#pragma unroll
  for (int i = 0; i < 32; i += 8) {
    int oy = bx * 32 + threadIdx.y + i;
    out[(size_t)oy * D_ + ox] = f2bf(tile[threadIdx.x][threadIdx.y + i]);
  }
}

// vp (B,S,H*DH) bf16 -> vt (B,H,DH,S) bf16. 64x64 LDS tile, chunk-swizzled.
__global__ __launch_bounds__(256) void transpose_v(const short* __restrict__ vp,
                                                   short* __restrict__ vt) {
  __shared__ __align__(16) short t[64 * 72];
  int tid = threadIdx.x;
  int bh = blockIdx.y, b = bh >> 4, h = bh & 15;
  int s0 = blockIdx.x * 64;
  int r = tid >> 2, cc = tid & 3;  // load: s-row r, 16-elem d-chunk cc
  const short* src = vp + ((size_t)(b * S_ + s0 + r)) * D_ + h * DH + cc * 16;
  s16x8 a = *(const s16x8*)src;
  s16x8 bb = *(const s16x8*)(src + 8);
  int pc = (cc ^ (r >> 4)) * 16;  // physical chunk
  *(s16x8*)&t[r * 72 + pc] = a;
  *(s16x8*)&t[r * 72 + pc + 8] = bb;
  __syncthreads();
  int d = tid >> 2, sc = (tid & 3) * 16;  // store: d-row, s-chunk
  s16x8 o0, o1;
#pragma unroll
  for (int j = 0; j < 8; ++j) {
    int row = sc + j;
    o0[j] = t[row * 72 + ((d >> 4) ^ (row >> 4)) * 16 + (d & 15)];
    int row2 = sc + 8 + j;
    o1[j] = t[row2 * 72 + ((d >> 4) ^ (row2 >> 4)) * 16 + (d & 15)];
  }
  short* dst = vt + ((size_t)(b * H_ + h) * DH + d) * S_ + s0 + sc;
  *(s16x8*)dst = o0;
  *(s16x8*)(dst + 8) = o1;
}

__device__ inline void gload_lds16(const void* g, void* l) {
  __builtin_amdgcn_global_load_lds(
      (const __attribute__((address_space(1))) unsigned*)g,
      (__attribute__((address_space(3))) unsigned*)l, 16, 0, 0);
}

#define BM 128
#define BN 128
#define BK 32

// Triple GEMM: slice z: C[z] = (A[z] * Bt[z]^T + bias[z]) * os[z]
__global__ __launch_bounds__(256) void gemm_bt3(
    const short* __restrict__ A0, const short* __restrict__ A1, const short* __restrict__ A2,
    const short* __restrict__ Bt0, const short* __restrict__ Bt1, const short* __restrict__ Bt2,
    const float* __restrict__ bs0, const float* __restrict__ bs1, const float* __restrict__ bs2,
    void* C0, void* C1, void* C2,
    int M, int N, int K, int f32out, float os0, float os1, float os2) {
  int z = blockIdx.y;
  const short* A = z == 0 ? A0 : (z == 1 ? A1 : A2);
  const short* Bt = z == 0 ? Bt0 : (z == 1 ? Bt1 : Bt2);
  const float* bias = z == 0 ? bs0 : (z == 1 ? bs1 : bs2);
  void* C = z == 0 ? C0 : (z == 1 ? C1 : C2);
  float oscale = z == 0 ? os0 : (z == 1 ? os1 : os2);

  __shared__ __align__(16) short As[BM * BK];
  __shared__ __align__(16) short Bs[BN * BK];
  int tid = threadIdx.x;
  int lane = tid & 63, wave = tid >> 6;
  int l15 = lane & 15, l4 = lane >> 4;
  int ntn = N / BN;
  int bm = blockIdx.x / ntn, bn = blockIdx.x % ntn;
  int row0 = bm * BM, col0 = bn * BN;
  int wm = (wave >> 1) * 64, wn = (wave & 1) * 64;

  f32x4 acc[4][4] = {};

  for (int k0 = 0; k0 < K; k0 += BK) {
    __syncthreads();
#pragma unroll
    for (int it = 0; it < 2; ++it) {
      int ch = it * 256 + tid;
      int r = ch >> 2, c = (ch & 3) * 8;
      int ldsbase = (it * 256 + wave * 64) * 8;  // elems; HW adds lane*16B
      gload_lds16(A + (size_t)(row0 + r) * K + k0 + c, &As[ldsbase]);
      gload_lds16(Bt + (size_t)(col0 + r) * K + k0 + c, &Bs[ldsbase]);
    }
    __syncthreads();
    s16x8 af[4], bf[4];
#pragma unroll
    for (int mf = 0; mf < 4; ++mf)
      af[mf] = *(const s16x8*)&As[(wm + mf * 16 + l15) * BK + l4 * 8];
#pragma unroll
    for (int nf = 0; nf < 4; ++nf)
      bf[nf] = *(const s16x8*)&Bs[(wn + nf * 16 + l15) * BK + l4 * 8];
#pragma unroll
    for (int mf = 0; mf < 4; ++mf)
#pragma unroll
      for (int nf = 0; nf < 4; ++nf)
        acc[mf][nf] = __builtin_amdgcn_mfma_f32_16x16x32_bf16(af[mf], bf[nf],
                                                              acc[mf][nf], 0, 0, 0);
  }

#pragma unroll
  for (int nf = 0; nf < 4; ++nf) {
    int gcol = col0 + wn + nf * 16 + l15;
    float bv = bias[gcol];
#pragma unroll
    for (int mf = 0; mf < 4; ++mf) {
#pragma unroll
      for (int r = 0; r < 4; ++r) {
        int grow = row0 + wm + mf * 16 + l4 * 4 + r;
        float v = (acc[mf][nf][r] + bv) * oscale;
        if (f32out)
          ((float*)C)[(size_t)grow * N + gcol] = v;
        else
          ((short*)C)[(size_t)grow * N + gcol] = f2bf(v);
      }
    }
  }
}

#define QB 64
#define NB 64
#define NTILES (S_ / NB)
#define M0_SHIFT 12.0f

// q (pre-scaled by 0.125*log2e), k bf16 (B,S,H*DH); VT bf16 (B,H,DH,S);
// mgp bf16 (B,S,S) (bits==0 <=> masked); ctx bf16 out.
// All three tiles (K, mgp, V^T) staged via global_load_lds, double-buffered,
// 16B-chunk XOR-swizzled. Swapped-operand QK^T and PV.
__global__ __launch_bounds__(256) void attn_fused(const short* __restrict__ Qp,
                                                  const short* __restrict__ Kp,
                                                  const short* __restrict__ VT,
                                                  const short* __restrict__ MGP,
                                                  short* __restrict__ ctx) {
  __shared__ __align__(16) short Ks[2][64 * 64];
  __shared__ __align__(16) short Ms[2][64 * 64];
  __shared__ __align__(16) short Vs[2][64 * 64];

  int tid = threadIdx.x, lane = tid & 63, wave = tid >> 6;
  int l15 = lane & 15, l4 = lane >> 4;
  int q0 = blockIdx.x * QB;
  int bh = blockIdx.y;
  int b = bh >> 4, h = bh & 15;
  int wq = wave * 16;

  const short* Qbase = Qp + (size_t)b * S_ * D_ + (size_t)h * DH;
  const short* Kbase = Kp + (size_t)b * S_ * D_ + (size_t)h * DH;
  const short* Vbase = VT + (size_t)(b * H_ + h) * DH * S_;  // rows d, stride S_
  const short* Mbase = MGP + (size_t)b * S_ * S_ + (size_t)q0 * S_;

  // staging: 512 chunks of 16B per 64x64 tile; LDS slot p of row r holds
  // source chunk p ^ (r&7)
  int i0 = tid, i1 = 256 + tid;
  int r0 = i0 >> 3, c0 = (i0 & 7) ^ (r0 & 7);
  int r1 = i1 >> 3, c1 = (i1 & 7) ^ (r1 & 7);
  int ldsA = wave * 512;         // elem offset of wave's chunk base, half 0
  int ldsB = 2048 + wave * 512;  // half 1

#define STAGE(kv0, buf)                                                    \
  do {                                                                     \
    gload_lds16(Kbase + (size_t)((kv0) + r0) * D_ + c0 * 8, &Ks[buf][ldsA]); \
    gload_lds16(Kbase + (size_t)((kv0) + r1) * D_ + c1 * 8, &Ks[buf][ldsB]); \
    gload_lds16(Mbase + (size_t)r0 * S_ + (kv0) + c0 * 8, &Ms[buf][ldsA]);   \
    gload_lds16(Mbase + (size_t)r1 * S_ + (kv0) + c1 * 8, &Ms[buf][ldsB]);   \
    gload_lds16(Vbase + (size_t)r0 * S_ + (kv0) + c0 * 8, &Vs[buf][ldsA]);   \
    gload_lds16(Vbase + (size_t)r1 * S_ + (kv0) + c1 * 8, &Vs[buf][ldsB]);   \
  } while (0)

  s16x8 qf[2];
#pragma unroll
  for (int ks = 0; ks < 2; ++ks)
    qf[ks] = *(const s16x8*)(Qbase + (size_t)(q0 + wq + l15) * D_ + ks * 32 + l4 * 8);

  float lsum = 0.f;
  f32x4 oacc[4] = {};

  STAGE(0, 0);

  int ql = wq + l15;
  int rowoff = ql * 64;
  int q7 = l15 & 7;
  int q7l = q7 << 1;

  for (int t = 0; t < NTILES; ++t) {
    int buf = t & 1;

    if (t + 1 < NTILES) {
      STAGE((t + 1) * NB, buf ^ 1);
      asm volatile("s_waitcnt vmcnt(6)" ::: "memory");
    } else {
      asm volatile("s_waitcnt vmcnt(0)" ::: "memory");
    }
    __builtin_amdgcn_s_barrier();
    __builtin_amdgcn_sched_barrier(0);

    // QK^T swapped: sacc[nf] = S^T[kv = nf*16 + l4*4 + r][q = wq + l15]
    f32x4 sacc[4] = {};
#pragma unroll
    for (int nf = 0; nf < 4; ++nf) {
      int R = nf * 16 + l15;
#pragma unroll
      for (int ks = 0; ks < 2; ++ks) {
        s16x8 kf = *(const s16x8*)&Ks[buf][R * 64 + (((ks * 4 + l4) ^ q7) * 8)];
        sacc[nf] = __builtin_amdgcn_mfma_f32_16x16x32_bf16(kf, qf[ks], sacc[nf], 0, 0, 0);
      }
    }

    // softmax (static shift): p = exp2(s - M0); P*gp back into Ms[buf]
#pragma unroll
    for (int nf = 0; nf < 4; ++nf) {
      int sl = ((nf * 4 + l4) ^ q7l) * 4;
      uint2 g2 = *(const uint2*)&Ms[buf][rowoff + sl];
      float gv0 = bfbits_lo(g2.x), gv1 = bfbits_hi(g2.x);
      float gv2 = bfbits_lo(g2.y), gv3 = bfbits_hi(g2.y);
      float e0 = exp2v(sacc[nf][0] - M0_SHIFT);
      float e1 = exp2v(sacc[nf][1] - M0_SHIFT);
      float e2 = exp2v(sacc[nf][2] - M0_SHIFT);
      float e3 = exp2v(sacc[nf][3] - M0_SHIFT);
      lsum += (gv0 != 0.f) ? e0 : 0.f;
      lsum += (gv1 != 0.f) ? e1 : 0.f;
      lsum += (gv2 != 0.f) ? e2 : 0.f;
      lsum += (gv3 != 0.f) ? e3 : 0.f;
      uint2 wp;
      wp.x = cvtpk(e0 * gv0, e1 * gv1);
      wp.y = cvtpk(e2 * gv2, e3 * gv3);
      *(uint2*)&Ms[buf][rowoff + sl] = wp;
    }

    // PV swapped: oacc[df] = O^T[d = df*16 + l4*4 + r][q = wq + l15]
#pragma unroll
    for (int ks = 0; ks < 2; ++ks) {
      s16x8 pa = *(const s16x8*)&Ms[buf][rowoff + (((ks * 4 + l4) ^ q7) * 8)];
#pragma unroll
      for (int df = 0; df < 4; ++df) {
        s16x8 vf = *(const s16x8*)&Vs[buf][(df * 16 + l15) * 64 +
                                           (((ks * 4 + l4) ^ q7) * 8)];
        oacc[df] = __builtin_amdgcn_mfma_f32_16x16x32_bf16(vf, pa, oacc[df], 0, 0, 0);
      }
    }

    asm volatile("s_waitcnt lgkmcnt(0)" ::: "memory");
    __builtin_amdgcn_s_barrier();
  }
#undef STAGE

  // epilogue: denominator reduce across the 4 l4 groups, store O^T/l
  lsum += __shfl_xor(lsum, 16);
  lsum += __shfl_xor(lsum, 32);
  float inv = 1.f / lsum;
  short* crow = ctx + ((size_t)(b * S_ + q0 + wq + l15)) * D_ + h * DH;
#pragma unroll
  for (int df = 0; df < 4; ++df) {
    uint2 o;
    o.x = cvtpk(oacc[df][0] * inv, oacc[df][1] * inv);
    o.y = cvtpk(oacc[df][2] * inv, oacc[df][3] * inv);
    *(uint2*)(crow + df * 16 + l4 * 4) = o;
  }
}

extern "C" void kernel_launch(void* const* d_in, const int* in_sizes, int n_in,
                              void* d_out, int out_size, void* d_ws, size_t ws_size,
                              hipStream_t stream) {
  const float* query = (const float*)d_in[0];
  const float* key_in = (const float*)d_in[1];
  const float* value = (const float*)d_in[2];
  const float* group_prob = (const float*)d_in[3];
  const int* mask = (const int*)d_in[4];
  const float* wq_k = (const float*)d_in[5];
  const float* wq_b = (const float*)d_in[6];
  const float* wk_k = (const float*)d_in[7];
  const float* wk_b = (const float*)d_in[8];
  const float* wv_k = (const float*)d_in[9];
  const float* wv_b = (const float*)d_in[10];
  const float* wo_k = (const float*)d_in[11];
  const float* wo_b = (const float*)d_in[12];
  float* out = (float*)d_out;

  short* ws = (short*)d_ws;
  const size_t NT = (size_t)B_ * S_ * D_;  // 4.19M elems
  short* qbf = ws;
  short* kbf = qbf + NT;
  short* vbf = kbf + NT;
  short* wqt = vbf + NT;
  short* wkt = wqt + (size_t)D_ * D_;
  short* wvt = wkt + (size_t)D_ * D_;
  short* wot = wvt + (size_t)D_ * D_;
  short* qp = wot + (size_t)D_ * D_;
  short* kp = qp + NT;
  short* vp = kp + NT;
  short* ctx = vp + NT;
  short* mgp = ws;   // reuses qbf+kbf (B*S*S == 2*NT); dead after projections
  short* vt = vbf;   // reuses vbf (NT);               dead after projections

  int nblk = (int)(NT / 4 / 256);
  cvt3_f32_bf16<<<dim3(nblk, 3), 256, 0, stream>>>(query, key_in, value,
                                                   qbf, kbf, vbf, (int)NT);

  dim3 tb(32, 8);
  transpose_cvt4<<<dim3(D_ / 32, D_ / 32, 4), tb, 0, stream>>>(
      wq_k, wk_k, wv_k, wo_k, wqt, wkt, wvt, wot);

  int M = B_ * S_;
  int gblocks = (M / BM) * (D_ / BN);
  const float QSCALE = 0.125f * 1.4426950408889634f;  // 1/sqrt(dh) * log2(e)
  gemm_bt3<<<dim3(gblocks, 3), 256, 0, stream>>>(
      qbf, kbf, vbf, wqt, wkt, wvt, wq_b, wk_b, wv_b, qp, kp, vp,
      M, D_, D_, 0, QSCALE, 1.0f, 1.0f);

  // both overwrite regions that are dead after the projections
  int nmg = B_ * S_ * S_;
  fuse_mgp<<<nmg / 4 / 256, 256, 0, stream>>>(mask, group_prob, mgp, nmg);
  transpose_v<<<dim3(S_ / 64, B_ * H_), 256, 0, stream>>>(vp, vt);

  dim3 ag(S_ / QB, B_ * H_);
  attn_fused<<<ag, 256, 0, stream>>>(qp, kp, vt, mgp, ctx);

  gemm_bt3<<<dim3(gblocks, 1), 256, 0, stream>>>(
      ctx, ctx, ctx, wot, wot, wot, wo_b, wo_b, wo_b, out, out, out,
      M, D_, D_, 1, 1.0f, 1.0f, 1.0f);
}